// Round 2
// baseline (404.430 us; speedup 1.0000x reference)
//
#include <hip/hip_runtime.h>

// PhiSoftMax: fused causal attention + Gumbel-sigmoid DAG mask, MI355X gfx950.
// B=2, L=S=2048, H=8, E=64. Memory-bound on phi/u (~140MB causal footprint).
// R1: phi/u register prefetch (double-buffer), 8-way S-split with in-block
// merge, per-batch P-scratch, deferred l-reduce, bitpacked hard_mask,
// XCD-affinity grid swizzle. ws usage < 30 MB.

#define Bz 2
#define Lz 2048
#define Sz 2048
#define Hz 8
#define Ez 64
#define NEG_BIG (-1e30f)

typedef __attribute__((ext_vector_type(8))) short short8;   // 8 bf16 (4 VGPRs)
typedef __attribute__((ext_vector_type(4))) short short4v;  // 4 bf16 (8B)
typedef __attribute__((ext_vector_type(4))) float f32x4;    // MFMA C/D frag

__device__ __forceinline__ float fast_rcp(float x) { return __builtin_amdgcn_rcpf(x); }

// float -> bf16 bits, round-to-nearest-even (finite inputs only)
__device__ __forceinline__ short f2bf(float x) {
    unsigned bits = __builtin_bit_cast(unsigned, x);
    bits += 0x7FFFu + ((bits >> 16) & 1u);
    return (short)(bits >> 16);
}

// ---------------- prepack: Q (scaled by 1/8) and K to bf16 [b,h,l,e] ----------------
__global__ void pack_qk(const float* __restrict__ q, const float* __restrict__ k,
                        short* __restrict__ qp, short* __restrict__ kp)
{
    const int t = blockIdx.x * 256 + threadIdx.x;   // 524288 float4 slots
    const float4 qv = ((const float4*)q)[t];
    const float4 kv = ((const float4*)k)[t];
    const int e4   = t & 15;
    const int rest = t >> 4;          // (b*L + l)*H + h
    const int h    = rest & 7;
    const int bl   = rest >> 3;
    const int b    = bl >> 11;
    const int l    = bl & 2047;
    const int o    = ((b*Hz + h)*Lz + l)*Ez + e4*4;
    short4v qo, ko;
    qo[0] = f2bf(qv.x*0.125f); qo[1] = f2bf(qv.y*0.125f);
    qo[2] = f2bf(qv.z*0.125f); qo[3] = f2bf(qv.w*0.125f);
    ko[0] = f2bf(kv.x); ko[1] = f2bf(kv.y); ko[2] = f2bf(kv.z); ko[3] = f2bf(kv.w);
    *(short4v*)&qp[o] = qo;
    *(short4v*)&kp[o] = ko;
}

// ---------------- prepack: V transposed to bf16 [b,h,e,s] ----------------
__global__ void pack_vt(const float* __restrict__ v, short* __restrict__ vt)
{
    const int blk = blockIdx.x;        // 1024 blocks: (b, h, s-tile of 32)
    const int st  = blk & 63;
    const int h   = (blk >> 6) & 7;
    const int b   = blk >> 9;
    const int s0  = st * 32;
    const int e   = threadIdx.x & 63;
    const int sc  = threadIdx.x >> 6;
    short8 ov;
#pragma unroll
    for (int j = 0; j < 8; ++j) {
        const int s = s0 + sc*8 + j;
        ov[j] = f2bf(v[((b*Sz + s)*Hz + h)*Ez + e]);
    }
    *(short8*)&vt[((b*Hz + h)*Ez + e)*Sz + s0 + sc*8] = ov;
}

// ---------------- prepack: hard_mask -> bitmask, word = 32 s-values ----------------
__global__ void pack_hm(const int* __restrict__ hm, unsigned* __restrict__ hmb)
{
    const int t = blockIdx.x * 256 + threadIdx.x;   // 131072 words (L*S/32)
    const int4* src = (const int4*)hm + t*8;
    unsigned w = 0;
#pragma unroll
    for (int i = 0; i < 8; ++i) {
        const int4 v = src[i];
        w |= (v.x != 0 ? 1u : 0u) << (i*4 + 0);
        w |= (v.y != 0 ? 1u : 0u) << (i*4 + 1);
        w |= (v.z != 0 ? 1u : 0u) << (i*4 + 2);
        w |= (v.w != 0 ? 1u : 0u) << (i*4 + 3);
    }
    hmb[t] = w;
}

// ---------------- main: flash attention + fused DAG mask ----------------
// grid 2048: blk -> h = blk&7 (XCD affinity), segpair = (blk>>3)&1, c = 127-(blk>>4)
// 4 waves/block = 4 consecutive S-segments (of 8) for the SAME (h,c) -> K/V L1/L2 reuse
// and in-block partial merge (2 global partial sets instead of 8).
__global__ __launch_bounds__(256, 2) void attn_main(
    const float* __restrict__ phi, const float* __restrict__ u,
    const unsigned* __restrict__ hmb, const int* __restrict__ causal_p,
    const float* __restrict__ log_tau_p, const float* __restrict__ thr_p,
    const short* __restrict__ qp, const short* __restrict__ kp,
    const short* __restrict__ vt,
    float* __restrict__ Og, float* __restrict__ Mg, float* __restrict__ Lg)
{
    const int lane    = threadIdx.x & 63;
    const int wslot   = threadIdx.x >> 6;
    const int h       = blockIdx.x & 7;
    const int r2      = blockIdx.x >> 3;
    const int segpair = r2 & 1;
    const int c       = 127 - (r2 >> 1);
    const int seg     = segpair*4 + wslot;
    const int l_base  = c * 16;
    const int ln      = lane & 15;
    const int quad    = lane >> 4;

    const int causal = *causal_p;
    float tau = __expf(*log_tau_p);
    tau = fminf(fmaxf(tau, 0.1f), 5.0f);
    const float inv_tau = 1.0f / tau;
    const float thr = fminf(fmaxf(*thr_p, 0.01f), 0.99f);

    // Q fragments (A-layout: A[m=ln][k=quad*8+j (+32k)])
    short8 qf[2][2];
#pragma unroll
    for (int b = 0; b < 2; ++b)
#pragma unroll
        for (int k = 0; k < 2; ++k)
            qf[b][k] = *(const short8*)&qp[((b*Hz + h)*Lz + l_base + ln)*Ez + k*32 + quad*8];

    f32x4 O[2][4];
    float m_r[2][4], l_r[2][4];   // l_r is per-LANE partial (alpha is row-uniform)
#pragma unroll
    for (int b = 0; b < 2; ++b) {
#pragma unroll
        for (int ne = 0; ne < 4; ++ne) { f32x4 z = {0.f,0.f,0.f,0.f}; O[b][ne] = z; }
#pragma unroll
        for (int r = 0; r < 4; ++r) { m_r[b][r] = -INFINITY; l_r[b][r] = 0.f; }
    }

    const int T = causal ? (((l_base + 15) >> 6) + 1) : (Sz >> 6);

    // per-wave, per-batch P scratch (16 rows x 72 halves, 16B-aligned rows)
    __shared__ __align__(16) short plds[4][2][16*72];

    const int mbase = (h*Lz + l_base + quad*4)*Sz + ln;

    auto ldmask = [&](int t, float (&P)[16], float (&U)[16]) {
        const int o0 = mbase + (t << 6);
#pragma unroll
        for (int nt = 0; nt < 4; ++nt)
#pragma unroll
            for (int r = 0; r < 4; ++r) {
                P[nt*4+r] = phi[o0 + r*Sz + nt*16];
                U[nt*4+r] = u[o0 + r*Sz + nt*16];
            }
    };

    auto process = [&](int t, const float (&P)[16], const float (&U)[16]) {
        const int s0 = t << 6;
        unsigned long long hmr[4];
#pragma unroll
        for (int r = 0; r < 4; ++r)
            hmr[r] = *(const unsigned long long*)&hmb[(l_base + quad*4 + r)*64 + (s0 >> 5)];

        float dg[16];
#pragma unroll
        for (int nt = 0; nt < 4; ++nt)
#pragma unroll
            for (int r = 0; r < 4; ++r) {
                const int l = l_base + quad*4 + r;
                const int s = s0 + nt*16 + ln;
                const float uv = U[nt*4+r];
                const float g  = __logf((uv + 1e-8f) * fast_rcp(1.0f - uv + 1e-8f));
                const float z  = (g + P[nt*4+r]) * inv_tau;
                const float sg = fast_rcp(1.0f + __expf(-z));
                const float d  = 1250.0f * fminf(sg - thr, 0.0f);   // scale*1e4/8 folded
                const bool open = (((hmr[r] >> (nt*16 + ln)) & 1ull) != 0ull)
                                  && !(causal && (s > l));
                dg[nt*4+r] = open ? d : -INFINITY;
            }

#pragma unroll
        for (int b = 0; b < 2; ++b) {
            f32x4 Sc[4];
#pragma unroll
            for (int nt = 0; nt < 4; ++nt) {
                const short8 k0 = *(const short8*)&kp[((b*Hz + h)*Sz + s0 + nt*16 + ln)*Ez + quad*8];
                const short8 k1 = *(const short8*)&kp[((b*Hz + h)*Sz + s0 + nt*16 + ln)*Ez + 32 + quad*8];
                f32x4 z4 = {0.f,0.f,0.f,0.f};
                z4 = __builtin_amdgcn_mfma_f32_16x16x32_bf16(qf[b][0], k0, z4, 0, 0, 0);
                Sc[nt] = __builtin_amdgcn_mfma_f32_16x16x32_bf16(qf[b][1], k1, Sc[nt] = z4, 0, 0, 0);
            }

            float mx[4];
#pragma unroll
            for (int r = 0; r < 4; ++r) mx[r] = -INFINITY;
#pragma unroll
            for (int nt = 0; nt < 4; ++nt)
#pragma unroll
                for (int r = 0; r < 4; ++r) {
                    Sc[nt][r] += dg[nt*4+r];
                    mx[r] = fmaxf(mx[r], Sc[nt][r]);
                }
#pragma unroll
            for (int r = 0; r < 4; ++r)
#pragma unroll
                for (int o = 1; o < 16; o <<= 1)
                    mx[r] = fmaxf(mx[r], __shfl_xor(mx[r], o, 16));

            float al[4];
#pragma unroll
            for (int r = 0; r < 4; ++r) {
                const float mn = fmaxf(m_r[b][r], mx[r]);
                al[r] = __expf(fmaxf(m_r[b][r], NEG_BIG) - fmaxf(mn, NEG_BIG));
                m_r[b][r] = mn;
            }

            short* myp = &plds[wslot][b][0];
            float ps[4] = {0.f, 0.f, 0.f, 0.f};
#pragma unroll
            for (int nt = 0; nt < 4; ++nt)
#pragma unroll
                for (int r = 0; r < 4; ++r) {
                    const float p = __expf(Sc[nt][r] - fmaxf(m_r[b][r], NEG_BIG));
                    ps[r] += p;
                    myp[(quad*4 + r)*72 + nt*16 + ln] = f2bf(p);
                }
#pragma unroll
            for (int r = 0; r < 4; ++r)
                l_r[b][r] = l_r[b][r] * al[r] + ps[r];   // per-lane partial; reduced at end
#pragma unroll
            for (int ne = 0; ne < 4; ++ne)
#pragma unroll
                for (int r = 0; r < 4; ++r)
                    O[b][ne][r] *= al[r];

            const short8 pa0 = *(const short8*)&myp[ln*72 + quad*8];
            const short8 pa1 = *(const short8*)&myp[ln*72 + 32 + quad*8];
#pragma unroll
            for (int ne = 0; ne < 4; ++ne) {
                const short8 v0 = *(const short8*)&vt[((b*Hz + h)*Ez + ne*16 + ln)*Sz + s0 + quad*8];
                const short8 v1 = *(const short8*)&vt[((b*Hz + h)*Ez + ne*16 + ln)*Sz + s0 + 32 + quad*8];
                O[b][ne] = __builtin_amdgcn_mfma_f32_16x16x32_bf16(pa0, v0, O[b][ne], 0, 0, 0);
                O[b][ne] = __builtin_amdgcn_mfma_f32_16x16x32_bf16(pa1, v1, O[b][ne], 0, 0, 0);
            }
        }
    };

    // software-pipelined main loop: prefetch next tile's phi/u while computing current
    float PA[16], UA[16], PB[16], UB[16];
    int t = seg;
    if (t < T) ldmask(t, PA, UA);
    int parity = 0;
    for (; t < T; t += 8, parity ^= 1) {
        if (parity == 0) {
            if (t + 8 < T) ldmask(t + 8, PB, UB);
            process(t, PA, UA);
        } else {
            if (t + 8 < T) ldmask(t + 8, PA, UA);
            process(t, PB, UB);
        }
    }

    // ---- epilogue: reduce l across lanes, in-block merge of the 4 segments ----
#pragma unroll
    for (int b = 0; b < 2; ++b)
#pragma unroll
        for (int r = 0; r < 4; ++r) {
            float lv = l_r[b][r];
#pragma unroll
            for (int o = 1; o < 16; o <<= 1) lv += __shfl_xor(lv, o, 16);
            l_r[b][r] = lv;
        }

    __shared__ float oslab[4][2][16][64];   // 32 KB
    __shared__ float mslab[4][2][16];
    __shared__ float lslab[4][2][16];
#pragma unroll
    for (int b = 0; b < 2; ++b) {
#pragma unroll
        for (int ne = 0; ne < 4; ++ne)
#pragma unroll
            for (int r = 0; r < 4; ++r)
                oslab[wslot][b][quad*4 + r][ne*16 + ln] = O[b][ne][r];
        if (ln == 0) {
#pragma unroll
            for (int r = 0; r < 4; ++r) {
                mslab[wslot][b][quad*4 + r] = m_r[b][r];
                lslab[wslot][b][quad*4 + r] = l_r[b][r];
            }
        }
    }
    __syncthreads();

    const int tb   = threadIdx.x >> 7;          // batch
    const int trow = (threadIdx.x >> 3) & 15;   // row in chunk
    const int teg  = threadIdx.x & 7;           // e-group of 8
    float mM = -INFINITY;
#pragma unroll
    for (int w = 0; w < 4; ++w) mM = fmaxf(mM, mslab[w][tb][trow]);
    const float mMg = fmaxf(mM, NEG_BIG);
    float wgt[4]; float lsum = 0.f;
#pragma unroll
    for (int w = 0; w < 4; ++w) {
        wgt[w] = __expf(fmaxf(mslab[w][tb][trow], NEG_BIG) - mMg);
        lsum += wgt[w] * lslab[w][tb][trow];
    }
    float acc[8];
#pragma unroll
    for (int e = 0; e < 8; ++e) acc[e] = 0.f;
#pragma unroll
    for (int w = 0; w < 4; ++w)
#pragma unroll
        for (int e = 0; e < 8; ++e)
            acc[e] += wgt[w] * oslab[w][tb][trow][teg*8 + e];

    const int lrow = l_base + trow;
    const int oidx = (((segpair*2 + tb)*Hz + h)*Lz + lrow)*Ez + teg*8;
    float4 o0, o1;
    o0.x = acc[0]; o0.y = acc[1]; o0.z = acc[2]; o0.w = acc[3];
    o1.x = acc[4]; o1.y = acc[5]; o1.z = acc[6]; o1.w = acc[7];
    *(float4*)&Og[oidx]     = o0;
    *(float4*)&Og[oidx + 4] = o1;
    if (teg == 0) {
        const int midx = ((segpair*2 + tb)*Hz + h)*Lz + lrow;
        Mg[midx] = mM;
        Lg[midx] = lsum;
    }
}

// ---------------- merge the 2 partial sets, normalize, write [b,l,h,e] ----------------
__global__ void merge2(const float* __restrict__ Og, const float* __restrict__ Mg,
                       const float* __restrict__ Lg, float* __restrict__ out)
{
    const int t = blockIdx.x * 256 + threadIdx.x;    // 524288 = B*L*H*E/4
    const int e4   = (t & 15) * 4;
    const int rest = t >> 4;
    const int h    = rest & 7;
    const int bl   = rest >> 3;
    const int b    = bl >> 11;
    const int l    = bl & 2047;

    const int i0 = ((0*2 + b)*Hz + h)*Lz + l;
    const int i1 = ((1*2 + b)*Hz + h)*Lz + l;
    const float m0 = Mg[i0], m1 = Mg[i1];
    const float l0 = Lg[i0], l1 = Lg[i1];
    const float m  = fmaxf(m0, m1);
    const float mg = fmaxf(m, NEG_BIG);
    const float w0 = __expf(fmaxf(m0, NEG_BIG) - mg);
    const float w1 = __expf(fmaxf(m1, NEG_BIG) - mg);
    const float den = w0*l0 + w1*l1;       // diagonal always open -> den > 0
    const float rd  = 1.0f / den;
    const float4 a = *(const float4*)&Og[i0*Ez + e4];
    const float4 c = *(const float4*)&Og[i1*Ez + e4];
    float4 res;
    res.x = (w0*a.x + w1*c.x) * rd;
    res.y = (w0*a.y + w1*c.y) * rd;
    res.z = (w0*a.z + w1*c.z) * rd;
    res.w = (w0*a.w + w1*c.w) * rd;
    *(float4*)&out[((b*Lz + l)*Hz + h)*Ez + e4] = res;
}

extern "C" void kernel_launch(void* const* d_in, const int* in_sizes, int n_in,
                              void* d_out, int out_size, void* d_ws, size_t ws_size,
                              hipStream_t stream)
{
    const float* q    = (const float*)d_in[0];
    const float* k    = (const float*)d_in[1];
    const float* v    = (const float*)d_in[2];
    const int*   caus = (const int*)d_in[6];
    const int*   hm   = (const int*)d_in[7];
    const float* phi  = (const float*)d_in[8];
    const float* ltau = (const float*)d_in[9];
    const float* thr  = (const float*)d_in[10];
    const float* u    = (const float*)d_in[11];

    char* ws = (char*)d_ws;
    short*    qp  = (short*)   (ws);                                  //  4 MB
    short*    kp  = (short*)   (ws + (size_t)( 4u << 20));            //  4 MB
    short*    vt  = (short*)   (ws + (size_t)( 8u << 20));            //  4 MB
    unsigned* hmb = (unsigned*)(ws + (size_t)(12u << 20));            // 512 KB
    float*    Og  = (float*)   (ws + (size_t)(13u << 20));            // 16 MB
    float*    Mg  = (float*)   (ws + (size_t)(29u << 20));            // 256 KB
    float*    Lg  = (float*)   (ws + (size_t)(29u << 20) + (256u << 10));

    pack_qk <<<2048, 256, 0, stream>>>(q, k, qp, kp);
    pack_vt <<<1024, 256, 0, stream>>>(v, vt);
    pack_hm <<< 512, 256, 0, stream>>>(hm, hmb);
    attn_main<<<2048, 256, 0, stream>>>(phi, u, hmb, caus, ltau, thr, qp, kp, vt, Og, Mg, Lg);
    merge2  <<<2048, 256, 0, stream>>>(Og, Mg, Lg, (float*)d_out);
}